// Round 6
// baseline (267.657 us; speedup 1.0000x reference)
//
#include <hip/hip_runtime.h>
#include <hip/hip_bf16.h>

// B=4, S=2048, E=512, H=8, D=64, F=2048
// Attention via exact Gaussian-kernel Taylor factorization (R=16 terms), V folded after k-sum.
// MLP via bf16 MFMA 16x16x32, 3-stage counted-vmcnt pipeline (T3+T4), XCD swizzle (T1).
// 5 kernel launches total (launch overhead ~10us each was ~40% of round-4 time).

#define Bsz 4
#define Ssz 2048
#define Esz 512
#define Hsz 8
#define Dsz 64
#define Fsz 2048
#define NR 16      // Taylor terms
#define NCH 16     // k-chunks
#define CHK 128    // k per chunk

typedef __attribute__((ext_vector_type(8))) short bf16x8;
typedef __attribute__((ext_vector_type(4))) float f32x4;

// 1/sqrt(n), n=1..15 (RS[0] unused)
__device__ __constant__ float RS[16] = {
    0.f, 1.0f, 0.70710678f, 0.57735027f, 0.5f, 0.44721360f, 0.40824829f,
    0.37796447f, 0.35355339f, 0.33333333f, 0.31622777f, 0.30151134f,
    0.28867513f, 0.27735010f, 0.26726124f, 0.25819889f};

static __device__ __forceinline__ void gload_lds16(const void* g, void* l) {
    __builtin_amdgcn_global_load_lds(
        (const __attribute__((address_space(1))) unsigned int*)g,
        (__attribute__((address_space(3))) unsigned int*)l, 16, 0, 0);
}

static __device__ __forceinline__ unsigned short f2bf(float f) {
    unsigned int b = __float_as_uint(f);
    b += 0x7FFFu + ((b >> 16) & 1u);
    return (unsigned short)(b >> 16);
}
static __device__ __forceinline__ float bf2f(unsigned short u) {
    return __int_as_float(((int)u) << 16);
}

// ---------------- K1: prep = LayerNorm(+Q/K, Xn bf16) | transpose W1 | transpose W2 ----------------
__global__ __launch_bounds__(256) void prep_kernel(
    const float* __restrict__ x,
    const float* __restrict__ Wq, const float* __restrict__ bq,
    const float* __restrict__ Wk, const float* __restrict__ bk,
    const float* __restrict__ W1, const float* __restrict__ W2,
    float* __restrict__ Qo, float* __restrict__ Ko, __hip_bfloat16* __restrict__ Xn,
    __hip_bfloat16* __restrict__ W1T, __hip_bfloat16* __restrict__ W2T)
{
    int bid = blockIdx.x;
    if (bid < 2048) {
        // ---- LayerNorm, wave per token ----
        int wid = threadIdx.x >> 6, lane = threadIdx.x & 63;
        int tok = bid * 4 + wid;
        int b = tok >> 11, s = tok & 2047;

        const float* xrow = x + (size_t)tok * Esz;
        float4 v0 = *(const float4*)&xrow[lane * 8];
        float4 v1 = *(const float4*)&xrow[lane * 8 + 4];

        float sum = v0.x + v0.y + v0.z + v0.w + v1.x + v1.y + v1.z + v1.w;
        #pragma unroll
        for (int off = 32; off > 0; off >>= 1) sum += __shfl_xor(sum, off);
        float mean = sum * (1.0f / 512.0f);

        float d[8] = {v0.x - mean, v0.y - mean, v0.z - mean, v0.w - mean,
                      v1.x - mean, v1.y - mean, v1.z - mean, v1.w - mean};
        float ss = 0.f;
        #pragma unroll
        for (int j = 0; j < 8; ++j) ss = fmaf(d[j], d[j], ss);
        #pragma unroll
        for (int off = 32; off > 0; off >>= 1) ss += __shfl_xor(ss, off);
        float inv = rsqrtf(ss * (1.0f / 512.0f) + 1e-5f);

        float xn[8];
        #pragma unroll
        for (int j = 0; j < 8; ++j) xn[j] = d[j] * inv;

        int h = lane >> 3, dsub = (lane & 7) * 8;
        union { bf16x8 v; unsigned short u[8]; } pk;
        #pragma unroll
        for (int j = 0; j < 8; ++j) pk.u[j] = f2bf(xn[j]);
        *(bf16x8*)((unsigned short*)Xn + (((size_t)(b * Hsz + h) * Ssz + s) * Dsz + dsub)) = pk.v;

        float4 wqa = *(const float4*)&Wq[h * 64 + dsub];
        float4 wqb = *(const float4*)&Wq[h * 64 + dsub + 4];
        float4 wka = *(const float4*)&Wk[h * 64 + dsub];
        float4 wkb = *(const float4*)&Wk[h * 64 + dsub + 4];
        float pq = xn[0]*wqa.x + xn[1]*wqa.y + xn[2]*wqa.z + xn[3]*wqa.w
                 + xn[4]*wqb.x + xn[5]*wqb.y + xn[6]*wqb.z + xn[7]*wqb.w;
        float pkv = xn[0]*wka.x + xn[1]*wka.y + xn[2]*wka.z + xn[3]*wka.w
                  + xn[4]*wkb.x + xn[5]*wkb.y + xn[6]*wkb.z + xn[7]*wkb.w;
        #pragma unroll
        for (int off = 1; off < 8; off <<= 1) {
            pq  += __shfl_xor(pq, off);
            pkv += __shfl_xor(pkv, off);
        }
        if ((lane & 7) == 0) {
            int bh = b * Hsz + h;
            Qo[bh * Ssz + s] = pq + bq[h];
            Ko[bh * Ssz + s] = pkv + bk[h];
        }
        return;
    }

    // ---- transposes (fp32 -> bf16): out[C][R] = in[R][C] ----
    __shared__ float tile[32][33];
    const float* in;
    __hip_bfloat16* outp;
    int R, C, bx, by;
    if (bid < 3072) {
        int tb = bid - 2048;
        in = W1; outp = W1T; R = Esz; C = Fsz;
        bx = tb & 63; by = tb >> 6;
    } else {
        int tb = bid - 3072;
        in = W2; outp = W2T; R = Fsz; C = Esz;
        bx = tb & 15; by = tb >> 4;
    }
    int t = threadIdx.x;
    int tc = t & 31, tr = t >> 5;
    #pragma unroll
    for (int i = 0; i < 4; ++i) {
        int rr = by * 32 + tr + i * 8, cc = bx * 32 + tc;
        tile[tr + i * 8][tc] = in[(size_t)rr * C + cc];
    }
    __syncthreads();
    #pragma unroll
    for (int i = 0; i < 4; ++i) {
        int ro = bx * 32 + tr + i * 8, co = by * 32 + tc;
        outp[(size_t)ro * R + co] = __float2bfloat16(tile[tc][tr + i * 8]);
    }
}

// ---------------- K2: moments (vectorized bf16x8 loads) + last-block-per-bh transform ----------------
// Gp[bh][chunk][n][68]; M[bh][n][68] (cols 0..63 = G@Wv + den*bv, col 64 = den)
__global__ __launch_bounds__(256) void attn_moments_fused(
    const float* __restrict__ Kv, const __hip_bfloat16* __restrict__ Xn,
    const float* __restrict__ Wv, const float* __restrict__ bvp,
    float* __restrict__ Gp, float* __restrict__ M, unsigned int* __restrict__ cnt)
{
    int bh = blockIdx.x >> 4, chunk = blockIdx.x & 15, h = bh & 7;
    int t = threadIdx.x;
    __shared__ float Wt[CHK][17];
    __shared__ float Gf[NR * 68];
    __shared__ int isLast;

    int k0 = chunk * CHK;
    if (t < CHK) {
        float kv = Kv[bh * Ssz + k0 + t];
        float wn = __expf(-0.125f * kv * kv);
        float half = 0.5f * kv;
        Wt[t][0] = wn;
        #pragma unroll
        for (int n = 1; n < NR; ++n) { wn *= half * RS[n]; Wt[t][n] = wn; }
    }
    __syncthreads();

    int w = t >> 6, lane = t & 63;
    int kk = lane >> 3, dg = lane & 7;   // 8 k-slots x 8 d-groups per wave
    int ng = w * 4;                       // this wave's 4 Taylor terms
    float acc[4][8] = {};
    const unsigned short* xb = (const unsigned short*)Xn + ((size_t)bh * Ssz + k0) * Dsz + dg * 8;
    for (int kc = 0; kc < CHK / 8; ++kc) {
        int kl = kc * 8 + kk;
        bf16x8 xv = *(const bf16x8*)&xb[(size_t)kl * Dsz];
        float xf[8];
        #pragma unroll
        for (int e = 0; e < 8; ++e) xf[e] = bf2f((unsigned short)xv[e]);
        #pragma unroll
        for (int n = 0; n < 4; ++n) {
            float wt = Wt[kl][ng + n];
            #pragma unroll
            for (int e = 0; e < 8; ++e) acc[n][e] = fmaf(wt, xf[e], acc[n][e]);
        }
    }
    // reduce over the 8 kk-slots (lane groups stride 8)
    #pragma unroll
    for (int off = 8; off < 64; off <<= 1)
        #pragma unroll
        for (int n = 0; n < 4; ++n)
            #pragma unroll
            for (int e = 0; e < 8; ++e)
                acc[n][e] += __shfl_xor(acc[n][e], off);
    if (kk == 0) {
        #pragma unroll
        for (int n = 0; n < 4; ++n) {
            float* gp = &Gp[(((size_t)bh * NCH + chunk) * NR + ng + n) * 68 + dg * 8];
            float4 lo = {acc[n][0], acc[n][1], acc[n][2], acc[n][3]};
            float4 hi = {acc[n][4], acc[n][5], acc[n][6], acc[n][7]};
            *(float4*)gp = lo;
            *(float4*)(gp + 4) = hi;
        }
    }
    if (t < NR) {
        float s = 0.f;
        for (int k = 0; k < CHK; ++k) s += Wt[k][t];
        Gp[(((size_t)bh * NCH + chunk) * NR + t) * 68 + 64] = s;
    }

    // ---- completion protocol: last chunk-block of this bh does reduce + Wv transform ----
    __threadfence();
    __syncthreads();
    if (t == 0) {
        unsigned int old = atomicAdd(&cnt[bh], 1u);
        isLast = (old == NCH - 1) ? 1 : 0;
    }
    __syncthreads();
    if (!isLast) return;
    __threadfence();

    for (int i = t; i < NR * 68; i += 256) {
        float s = 0.f;
        #pragma unroll
        for (int c = 0; c < NCH; ++c)
            s += Gp[(((size_t)bh * NCH + c) * NR) * 68 + i];
        Gf[i] = s;
    }
    __syncthreads();
    #pragma unroll
    for (int rep = 0; rep < 4; ++rep) {
        int o = t + rep * 256;
        int n = o >> 6, dd = o & 63;
        float den = Gf[n * 68 + 64];
        float accv = den * bvp[h * 64 + dd];
        const float* wv = Wv + ((size_t)h * 64) * 64 + dd;
        #pragma unroll
        for (int e = 0; e < 64; ++e) accv = fmaf(Gf[n * 68 + e], wv[(size_t)e * 64], accv);
        M[(size_t)bh * NR * 68 + n * 68 + dd] = accv;
        if (dd == 0) M[(size_t)bh * NR * 68 + n * 68 + 64] = den;
    }
}

// ---------------- K3: apply Q-side, write head_out as bf16 [8192,512] ----------------
__global__ __launch_bounds__(256) void attn_apply(
    const float* __restrict__ Qv, const float* __restrict__ M, __hip_bfloat16* __restrict__ A1)
{
    int tok = blockIdx.x;
    int b = tok >> 11, s = tok & 2047;
    int t = threadIdx.x;
    #pragma unroll
    for (int rep = 0; rep < 2; ++rep) {
        int e = t + rep * 256;
        int h = e >> 6, dd = e & 63;
        int bh = b * 8 + h;
        float q = Qv[bh * Ssz + s];
        const float* Mb = M + (size_t)bh * NR * 68;
        float half = 0.5f * q;
        float phi = 1.0f;
        float num = Mb[dd], den = Mb[64];
        #pragma unroll
        for (int n = 1; n < NR; ++n) {
            phi *= half * RS[n];
            num = fmaf(phi, Mb[n * 68 + dd], num);
            den = fmaf(phi, Mb[n * 68 + 64], den);
        }
        A1[(size_t)tok * Esz + e] = __float2bfloat16(num / den);
    }
}

// ---------------- K4/K5: bf16 MFMA GEMM, 3-stage counted-vmcnt pipeline ----------------
// C = A[M,K] * Bt[N,K]^T.  128 x BN tile, BK=32, 4 waves (2x2).
// EPI=0: out bf16 = gelu(acc+bias). EPI=1: out f32 = acc+bias+resid.
template <int KDIM, int NDIM, int BN, int EPI>
__global__ __launch_bounds__(256) void gemm_bf16(
    const __hip_bfloat16* __restrict__ A, const __hip_bfloat16* __restrict__ Bt,
    const float* __restrict__ bias, const float* __restrict__ resid,
    void* __restrict__ Out)
{
    constexpr int NT = KDIM / 32;
    constexpr int NWGX = NDIM / BN;
    constexpr int NWG = NWGX * 64;           // M/128 = 64
    constexpr int FN = BN / 32;              // N-frags per wave: 4 (BN=128) or 2 (BN=64)

    __shared__ unsigned short As[3][128][32];
    __shared__ unsigned short Bs[3][BN][32];

    int t = threadIdx.x;
    int w = t >> 6, lane = t & 63;
    int wr = w >> 1, wc = w & 1;

    // XCD-aware bijective swizzle (NWG % 8 == 0)
    int orig = blockIdx.x;
    int swz = (orig & 7) * (NWG / 8) + (orig >> 3);
    int bm = (swz / NWGX) * 128;
    int bn = (swz % NWGX) * BN;

    f32x4 acc[4][FN] = {};
    const int r = t >> 2, cg = (t & 3) * 8;

    auto stage = [&](int kt, int buf) {
        int k0 = kt * 32;
        gload_lds16(&A[(size_t)(bm + r) * KDIM + k0 + cg], &As[buf][r][cg]);
        gload_lds16(&A[(size_t)(bm + r + 64) * KDIM + k0 + cg], &As[buf][r + 64][cg]);
        gload_lds16(&Bt[(size_t)(bn + r) * KDIM + k0 + cg], &Bs[buf][r][cg]);
        if constexpr (BN == 128)
            gload_lds16(&Bt[(size_t)(bn + r + 64) * KDIM + k0 + cg], &Bs[buf][r + 64][cg]);
    };
    auto wait_stage = [&](bool more_inflight) {
        if (more_inflight) {
            if constexpr (BN == 128) asm volatile("s_waitcnt vmcnt(4)" ::: "memory");
            else                     asm volatile("s_waitcnt vmcnt(3)" ::: "memory");
        } else {
            asm volatile("s_waitcnt vmcnt(0)" ::: "memory");
        }
    };

    stage(0, 0);
    stage(1, 1);
    wait_stage(true);                    // stage 0 done; stage 1 may fly
    __builtin_amdgcn_s_barrier();
    __builtin_amdgcn_sched_barrier(0);

    for (int kt = 0; kt < NT; ++kt) {
        int cb = kt % 3;
        if (kt + 2 < NT) stage(kt + 2, (kt + 2) % 3);

        bf16x8 af[4], bfr[FN];
        #pragma unroll
        for (int i = 0; i < 4; ++i)
            af[i] = *(const bf16x8*)&As[cb][wr * 64 + i * 16 + (lane & 15)][(lane >> 4) * 8];
        #pragma unroll
        for (int j = 0; j < FN; ++j)
            bfr[j] = *(const bf16x8*)&Bs[cb][wc * (BN / 2) + j * 16 + (lane & 15)][(lane >> 4) * 8];
        #pragma unroll
        for (int i = 0; i < 4; ++i)
            #pragma unroll
            for (int j = 0; j < FN; ++j)
                acc[i][j] = __builtin_amdgcn_mfma_f32_16x16x32_bf16(af[i], bfr[j], acc[i][j], 0, 0, 0);

        if (kt + 1 < NT) {
            wait_stage(kt + 2 < NT);     // next tile staged; deeper prefetch may stay in flight
            __builtin_amdgcn_s_barrier();
            __builtin_amdgcn_sched_barrier(0);
        }
    }

    int col0 = lane & 15, rowg = lane >> 4;
    #pragma unroll
    for (int i = 0; i < 4; ++i) {
        #pragma unroll
        for (int j = 0; j < FN; ++j) {
            #pragma unroll
            for (int v = 0; v < 4; ++v) {
                int m = bm + wr * 64 + i * 16 + rowg * 4 + v;
                int n = bn + wc * (BN / 2) + j * 16 + col0;
                float val = acc[i][j][v] + bias[n];
                if (EPI == 0) {
                    float g = 0.5f * val * (1.0f + erff(val * 0.70710678f));
                    ((__hip_bfloat16*)Out)[(size_t)m * NDIM + n] = __float2bfloat16(g);
                } else {
                    size_t idx = (size_t)m * NDIM + n;
                    ((float*)Out)[idx] = val + resid[idx];
                }
            }
        }
    }
}

extern "C" void kernel_launch(void* const* d_in, const int* in_sizes, int n_in,
                              void* d_out, int out_size, void* d_ws, size_t ws_size,
                              hipStream_t stream) {
    const float* x  = (const float*)d_in[0];
    const float* Wv = (const float*)d_in[1];
    const float* bv = (const float*)d_in[2];
    const float* Wq = (const float*)d_in[3];
    const float* bq = (const float*)d_in[4];
    const float* Wk = (const float*)d_in[5];
    const float* bk = (const float*)d_in[6];
    const float* W1 = (const float*)d_in[7];
    const float* b1 = (const float*)d_in[8];
    const float* W2 = (const float*)d_in[9];
    const float* b2 = (const float*)d_in[10];
    float* out = (float*)d_out;

    char* ws = (char*)d_ws;
    float* Qb    = (float*)(ws + 0);                         // 256 KB
    float* Kb    = (float*)(ws + 262144);                    // 256 KB
    __hip_bfloat16* Xn = (__hip_bfloat16*)(ws + 524288);     // 8 MB  [bh][s][d]
    float* Gp    = (float*)(ws + 8912896);                   // 2.23 MB (dead after moments)
    __hip_bfloat16* A1 = (__hip_bfloat16*)(ws + 8912896);    // 8 MB, overlaps Gp (written later)
    float* Mfull = (float*)(ws + 17301504);                  // 139 KB
    unsigned int* cnt = (unsigned int*)(ws + 17440768);      // 128 B
    __hip_bfloat16* W1T  = (__hip_bfloat16*)(ws + 17441024); // 2 MB
    __hip_bfloat16* W2T  = (__hip_bfloat16*)(ws + 19538176); // 2 MB
    __hip_bfloat16* hbuf = (__hip_bfloat16*)(ws + 21635328); // 32 MB

    hipMemsetAsync(cnt, 0, 32 * sizeof(unsigned int), stream);
    prep_kernel<<<dim3(4096), 256, 0, stream>>>(x, Wq, bq, Wk, bk, W1, W2, Qb, Kb, Xn, W1T, W2T);
    attn_moments_fused<<<dim3(Bsz * Hsz * NCH), 256, 0, stream>>>(Kb, Xn, Wv, bv, Gp, Mfull, cnt);
    attn_apply<<<dim3(Bsz * Ssz), 256, 0, stream>>>(Qb, Mfull, A1);
    gemm_bf16<Esz, Fsz, 128, 0><<<dim3(1024), 256, 0, stream>>>(A1, W1T, b1, nullptr, hbuf);
    gemm_bf16<Fsz, Esz, 64, 1><<<dim3(512), 256, 0, stream>>>(hbuf, W2T, b2, x, out);
}

// Round 8
// 217.597 us; speedup vs baseline: 1.2301x; 1.2301x over previous
//
#include <hip/hip_runtime.h>
#include <hip/hip_bf16.h>

// B=4, S=2048, E=512, H=8, D=64, F=2048
// Attention via exact Gaussian-kernel Taylor factorization (R=16 terms), V folded after k-sum.
// Moments: ONE block per (b,h) -> block-local G + Wv transform, no cross-block fences
// (round-6's __threadfence protocol cost 85us of idle L2-writeback serialization).
// MLP via bf16 MFMA 16x16x32, 3-stage counted-vmcnt pipeline (T3+T4), XCD swizzle (T1).

#define Bsz 4
#define Ssz 2048
#define Esz 512
#define Hsz 8
#define Dsz 64
#define Fsz 2048
#define NR 16      // Taylor terms

typedef __attribute__((ext_vector_type(8))) short bf16x8;
typedef __attribute__((ext_vector_type(4))) float f32x4;

// 1/sqrt(n), n=1..15 (RS[0] unused)
__device__ __constant__ float RS[16] = {
    0.f, 1.0f, 0.70710678f, 0.57735027f, 0.5f, 0.44721360f, 0.40824829f,
    0.37796447f, 0.35355339f, 0.33333333f, 0.31622777f, 0.30151134f,
    0.28867513f, 0.27735010f, 0.26726124f, 0.25819889f};

static __device__ __forceinline__ void gload_lds16(const void* g, void* l) {
    __builtin_amdgcn_global_load_lds(
        (const __attribute__((address_space(1))) unsigned int*)g,
        (__attribute__((address_space(3))) unsigned int*)l, 16, 0, 0);
}

static __device__ __forceinline__ unsigned short f2bf(float f) {
    unsigned int b = __float_as_uint(f);
    b += 0x7FFFu + ((b >> 16) & 1u);
    return (unsigned short)(b >> 16);
}
static __device__ __forceinline__ float bf2f(unsigned short u) {
    return __int_as_float(((int)u) << 16);
}

// ---------------- K1: prep = LayerNorm(+Q/K, Xn bf16) | transpose W1 | transpose W2 ----------------
__global__ __launch_bounds__(256) void prep_kernel(
    const float* __restrict__ x,
    const float* __restrict__ Wq, const float* __restrict__ bq,
    const float* __restrict__ Wk, const float* __restrict__ bk,
    const float* __restrict__ W1, const float* __restrict__ W2,
    float* __restrict__ Qo, float* __restrict__ Ko, __hip_bfloat16* __restrict__ Xn,
    __hip_bfloat16* __restrict__ W1T, __hip_bfloat16* __restrict__ W2T)
{
    int bid = blockIdx.x;
    if (bid < 2048) {
        // ---- LayerNorm, wave per token ----
        int wid = threadIdx.x >> 6, lane = threadIdx.x & 63;
        int tok = bid * 4 + wid;
        int b = tok >> 11, s = tok & 2047;

        const float* xrow = x + (size_t)tok * Esz;
        float4 v0 = *(const float4*)&xrow[lane * 8];
        float4 v1 = *(const float4*)&xrow[lane * 8 + 4];

        float sum = v0.x + v0.y + v0.z + v0.w + v1.x + v1.y + v1.z + v1.w;
        #pragma unroll
        for (int off = 32; off > 0; off >>= 1) sum += __shfl_xor(sum, off);
        float mean = sum * (1.0f / 512.0f);

        float d[8] = {v0.x - mean, v0.y - mean, v0.z - mean, v0.w - mean,
                      v1.x - mean, v1.y - mean, v1.z - mean, v1.w - mean};
        float ss = 0.f;
        #pragma unroll
        for (int j = 0; j < 8; ++j) ss = fmaf(d[j], d[j], ss);
        #pragma unroll
        for (int off = 32; off > 0; off >>= 1) ss += __shfl_xor(ss, off);
        float inv = rsqrtf(ss * (1.0f / 512.0f) + 1e-5f);

        float xn[8];
        #pragma unroll
        for (int j = 0; j < 8; ++j) xn[j] = d[j] * inv;

        int h = lane >> 3, dsub = (lane & 7) * 8;
        union { bf16x8 v; unsigned short u[8]; } pk;
        #pragma unroll
        for (int j = 0; j < 8; ++j) pk.u[j] = f2bf(xn[j]);
        *(bf16x8*)((unsigned short*)Xn + (((size_t)(b * Hsz + h) * Ssz + s) * Dsz + dsub)) = pk.v;

        float4 wqa = *(const float4*)&Wq[h * 64 + dsub];
        float4 wqb = *(const float4*)&Wq[h * 64 + dsub + 4];
        float4 wka = *(const float4*)&Wk[h * 64 + dsub];
        float4 wkb = *(const float4*)&Wk[h * 64 + dsub + 4];
        float pq = xn[0]*wqa.x + xn[1]*wqa.y + xn[2]*wqa.z + xn[3]*wqa.w
                 + xn[4]*wqb.x + xn[5]*wqb.y + xn[6]*wqb.z + xn[7]*wqb.w;
        float pkv = xn[0]*wka.x + xn[1]*wka.y + xn[2]*wka.z + xn[3]*wka.w
                  + xn[4]*wkb.x + xn[5]*wkb.y + xn[6]*wkb.z + xn[7]*wkb.w;
        #pragma unroll
        for (int off = 1; off < 8; off <<= 1) {
            pq  += __shfl_xor(pq, off);
            pkv += __shfl_xor(pkv, off);
        }
        if ((lane & 7) == 0) {
            int bh = b * Hsz + h;
            Qo[bh * Ssz + s] = pq + bq[h];
            Ko[bh * Ssz + s] = pkv + bk[h];
        }
        return;
    }

    // ---- transposes (fp32 -> bf16): out[C][R] = in[R][C] ----
    __shared__ float tile[32][33];
    const float* in;
    __hip_bfloat16* outp;
    int R, C, bx, by;
    if (bid < 3072) {
        int tb = bid - 2048;
        in = W1; outp = W1T; R = Esz; C = Fsz;
        bx = tb & 63; by = tb >> 6;
    } else {
        int tb = bid - 3072;
        in = W2; outp = W2T; R = Fsz; C = Esz;
        bx = tb & 15; by = tb >> 4;
    }
    int t = threadIdx.x;
    int tc = t & 31, tr = t >> 5;
    #pragma unroll
    for (int i = 0; i < 4; ++i) {
        int rr = by * 32 + tr + i * 8, cc = bx * 32 + tc;
        tile[tr + i * 8][tc] = in[(size_t)rr * C + cc];
    }
    __syncthreads();
    #pragma unroll
    for (int i = 0; i < 4; ++i) {
        int ro = bx * 32 + tr + i * 8, co = by * 32 + tc;
        outp[(size_t)ro * R + co] = __float2bfloat16(tile[tc][tr + i * 8]);
    }
}

// ---------------- K2: moments, ONE block per bh (block-local, no fences) ----------------
// M[bh][n][68]: cols 0..63 = G[n,:]@Wv[h] + den_n*bv[h,:], col 64 = den_n
__global__ __launch_bounds__(512) void attn_moments_block(
    const float* __restrict__ Kv, const __hip_bfloat16* __restrict__ Xn,
    const float* __restrict__ Wv, const float* __restrict__ bvp,
    float* __restrict__ M)
{
    int bh = blockIdx.x, h = bh & 7;
    int t = threadIdx.x;
    __shared__ float Wt[512][17];       // per-k Taylor weights, one chunk of 512 k
    __shared__ float Gf[NR * 68];

    int w = t >> 6, lane = t & 63;
    int kk = lane >> 3, dg = lane & 7;  // wave: 8 k-slots x 8 d-groups
    int ng = w * 2;                     // this wave's 2 Taylor terms
    float acc[2][8] = {};
    float dacc[2] = {};                 // den partials (same across dg; kk-reduced later)

    const unsigned short* xb = (const unsigned short*)Xn + (size_t)bh * Ssz * Dsz + dg * 8;

    for (int c = 0; c < Ssz / 512; ++c) {
        int k0 = c * 512;
        float kv = Kv[bh * Ssz + k0 + t];
        float wn = __expf(-0.125f * kv * kv);
        float half = 0.5f * kv;
        __syncthreads();                // previous chunk's Wt fully consumed
        Wt[t][0] = wn;
        #pragma unroll
        for (int n = 1; n < NR; ++n) { wn *= half * RS[n]; Wt[t][n] = wn; }
        __syncthreads();

        for (int kc = 0; kc < 512 / 8; ++kc) {
            int kl = kc * 8 + kk;
            bf16x8 xv = *(const bf16x8*)&xb[(size_t)(k0 + kl) * Dsz];
            float xf[8];
            #pragma unroll
            for (int e = 0; e < 8; ++e) xf[e] = bf2f((unsigned short)xv[e]);
            #pragma unroll
            for (int n = 0; n < 2; ++n) {
                float wt = Wt[kl][ng + n];
                dacc[n] += wt;
                #pragma unroll
                for (int e = 0; e < 8; ++e) acc[n][e] = fmaf(wt, xf[e], acc[n][e]);
            }
        }
    }

    // reduce over the 8 kk-slots (lanes strided by 8)
    #pragma unroll
    for (int off = 8; off < 64; off <<= 1) {
        #pragma unroll
        for (int n = 0; n < 2; ++n) {
            dacc[n] += __shfl_xor(dacc[n], off);
            #pragma unroll
            for (int e = 0; e < 8; ++e) acc[n][e] += __shfl_xor(acc[n][e], off);
        }
    }
    if (lane < 8) {                     // kk==0 lanes; lane == dg
        #pragma unroll
        for (int n = 0; n < 2; ++n) {
            float* gp = &Gf[(ng + n) * 68 + dg * 8];
            float4 lo = {acc[n][0], acc[n][1], acc[n][2], acc[n][3]};
            float4 hi = {acc[n][4], acc[n][5], acc[n][6], acc[n][7]};
            *(float4*)gp = lo;
            *(float4*)(gp + 4) = hi;
        }
    }
    if (lane == 0) {
        #pragma unroll
        for (int n = 0; n < 2; ++n) Gf[(ng + n) * 68 + 64] = dacc[n];
    }
    __syncthreads();

    // transform: M[n,d] = G[n,:]@Wv[h][:,d] + den_n*bv[h,d]
    #pragma unroll
    for (int rep = 0; rep < 2; ++rep) {
        int o = t + rep * 512;          // 1024 outputs
        int n = o >> 6, dd = o & 63;
        float den = Gf[n * 68 + 64];
        float accv = den * bvp[h * 64 + dd];
        const float* wv = Wv + ((size_t)h * 64) * 64 + dd;
        #pragma unroll
        for (int e = 0; e < 64; ++e) accv = fmaf(Gf[n * 68 + e], wv[(size_t)e * 64], accv);
        M[(size_t)bh * NR * 68 + n * 68 + dd] = accv;
        if (dd == 0) M[(size_t)bh * NR * 68 + n * 68 + 64] = den;
    }
}

// ---------------- K3: apply Q-side, write head_out as bf16 [8192,512] ----------------
__global__ __launch_bounds__(256) void attn_apply(
    const float* __restrict__ Qv, const float* __restrict__ M, __hip_bfloat16* __restrict__ A1)
{
    int tok = blockIdx.x;
    int b = tok >> 11, s = tok & 2047;
    int t = threadIdx.x;
    #pragma unroll
    for (int rep = 0; rep < 2; ++rep) {
        int e = t + rep * 256;
        int h = e >> 6, dd = e & 63;
        int bh = b * 8 + h;
        float q = Qv[bh * Ssz + s];
        const float* Mb = M + (size_t)bh * NR * 68;
        float half = 0.5f * q;
        float phi = 1.0f;
        float num = Mb[dd], den = Mb[64];
        #pragma unroll
        for (int n = 1; n < NR; ++n) {
            phi *= half * RS[n];
            num = fmaf(phi, Mb[n * 68 + dd], num);
            den = fmaf(phi, Mb[n * 68 + 64], den);
        }
        A1[(size_t)tok * Esz + e] = __float2bfloat16(num / den);
    }
}

// ---------------- K4/K5: bf16 MFMA GEMM, 3-stage counted-vmcnt pipeline ----------------
// C = A[M,K] * Bt[N,K]^T.  128 x BN tile, BK=32, 4 waves (2x2).
// EPI=0: out bf16 = gelu(acc+bias). EPI=1: out f32 = acc+bias+resid.
template <int KDIM, int NDIM, int BN, int EPI>
__global__ __launch_bounds__(256) void gemm_bf16(
    const __hip_bfloat16* __restrict__ A, const __hip_bfloat16* __restrict__ Bt,
    const float* __restrict__ bias, const float* __restrict__ resid,
    void* __restrict__ Out)
{
    constexpr int NT = KDIM / 32;
    constexpr int NWGX = NDIM / BN;
    constexpr int NWG = NWGX * 64;           // M/128 = 64
    constexpr int FN = BN / 32;              // N-frags per wave: 4 (BN=128) or 2 (BN=64)

    __shared__ unsigned short As[3][128][32];
    __shared__ unsigned short Bs[3][BN][32];

    int t = threadIdx.x;
    int w = t >> 6, lane = t & 63;
    int wr = w >> 1, wc = w & 1;

    // XCD-aware bijective swizzle (NWG % 8 == 0)
    int orig = blockIdx.x;
    int swz = (orig & 7) * (NWG / 8) + (orig >> 3);
    int bm = (swz / NWGX) * 128;
    int bn = (swz % NWGX) * BN;

    f32x4 acc[4][FN] = {};
    const int r = t >> 2, cg = (t & 3) * 8;

    auto stage = [&](int kt, int buf) {
        int k0 = kt * 32;
        gload_lds16(&A[(size_t)(bm + r) * KDIM + k0 + cg], &As[buf][r][cg]);
        gload_lds16(&A[(size_t)(bm + r + 64) * KDIM + k0 + cg], &As[buf][r + 64][cg]);
        gload_lds16(&Bt[(size_t)(bn + r) * KDIM + k0 + cg], &Bs[buf][r][cg]);
        if constexpr (BN == 128)
            gload_lds16(&Bt[(size_t)(bn + r + 64) * KDIM + k0 + cg], &Bs[buf][r + 64][cg]);
    };
    auto wait_stage = [&](bool more_inflight) {
        if (more_inflight) {
            if constexpr (BN == 128) asm volatile("s_waitcnt vmcnt(4)" ::: "memory");
            else                     asm volatile("s_waitcnt vmcnt(3)" ::: "memory");
        } else {
            asm volatile("s_waitcnt vmcnt(0)" ::: "memory");
        }
    };

    stage(0, 0);
    stage(1, 1);
    wait_stage(true);                    // stage 0 done; stage 1 may fly
    __builtin_amdgcn_s_barrier();
    __builtin_amdgcn_sched_barrier(0);

    for (int kt = 0; kt < NT; ++kt) {
        int cb = kt % 3;
        if (kt + 2 < NT) stage(kt + 2, (kt + 2) % 3);

        bf16x8 af[4], bfr[FN];
        #pragma unroll
        for (int i = 0; i < 4; ++i)
            af[i] = *(const bf16x8*)&As[cb][wr * 64 + i * 16 + (lane & 15)][(lane >> 4) * 8];
        #pragma unroll
        for (int j = 0; j < FN; ++j)
            bfr[j] = *(const bf16x8*)&Bs[cb][wc * (BN / 2) + j * 16 + (lane & 15)][(lane >> 4) * 8];
        #pragma unroll
        for (int i = 0; i < 4; ++i)
            #pragma unroll
            for (int j = 0; j < FN; ++j)
                acc[i][j] = __builtin_amdgcn_mfma_f32_16x16x32_bf16(af[i], bfr[j], acc[i][j], 0, 0, 0);

        if (kt + 1 < NT) {
            wait_stage(kt + 2 < NT);     // next tile staged; deeper prefetch may stay in flight
            __builtin_amdgcn_s_barrier();
            __builtin_amdgcn_sched_barrier(0);
        }
    }

    int col0 = lane & 15, rowg = lane >> 4;
    #pragma unroll
    for (int i = 0; i < 4; ++i) {
        #pragma unroll
        for (int j = 0; j < FN; ++j) {
            #pragma unroll
            for (int v = 0; v < 4; ++v) {
                int m = bm + wr * 64 + i * 16 + rowg * 4 + v;
                int n = bn + wc * (BN / 2) + j * 16 + col0;
                float val = acc[i][j][v] + bias[n];
                if (EPI == 0) {
                    float g = 0.5f * val * (1.0f + erff(val * 0.70710678f));
                    ((__hip_bfloat16*)Out)[(size_t)m * NDIM + n] = __float2bfloat16(g);
                } else {
                    size_t idx = (size_t)m * NDIM + n;
                    ((float*)Out)[idx] = val + resid[idx];
                }
            }
        }
    }
}

extern "C" void kernel_launch(void* const* d_in, const int* in_sizes, int n_in,
                              void* d_out, int out_size, void* d_ws, size_t ws_size,
                              hipStream_t stream) {
    const float* x  = (const float*)d_in[0];
    const float* Wv = (const float*)d_in[1];
    const float* bv = (const float*)d_in[2];
    const float* Wq = (const float*)d_in[3];
    const float* bq = (const float*)d_in[4];
    const float* Wk = (const float*)d_in[5];
    const float* bk = (const float*)d_in[6];
    const float* W1 = (const float*)d_in[7];
    const float* b1 = (const float*)d_in[8];
    const float* W2 = (const float*)d_in[9];
    const float* b2 = (const float*)d_in[10];
    float* out = (float*)d_out;

    char* ws = (char*)d_ws;
    float* Qb    = (float*)(ws + 0);                         // 256 KB
    float* Kb    = (float*)(ws + 262144);                    // 256 KB
    __hip_bfloat16* Xn = (__hip_bfloat16*)(ws + 524288);     // 8 MB  [bh][s][d]
    __hip_bfloat16* A1 = (__hip_bfloat16*)(ws + 8912896);    // 8 MB
    float* Mfull = (float*)(ws + 17301504);                  // 139 KB
    __hip_bfloat16* W1T  = (__hip_bfloat16*)(ws + 17441024); // 2 MB
    __hip_bfloat16* W2T  = (__hip_bfloat16*)(ws + 19538176); // 2 MB
    __hip_bfloat16* hbuf = (__hip_bfloat16*)(ws + 21635328); // 32 MB

    prep_kernel<<<dim3(4096), 256, 0, stream>>>(x, Wq, bq, Wk, bk, W1, W2, Qb, Kb, Xn, W1T, W2T);
    attn_moments_block<<<dim3(Bsz * Hsz), 512, 0, stream>>>(Kb, Xn, Wv, bv, Mfull);
    attn_apply<<<dim3(Bsz * Ssz), 256, 0, stream>>>(Qb, Mfull, A1);
    gemm_bf16<Esz, Fsz, 128, 0><<<dim3(1024), 256, 0, stream>>>(A1, W1T, b1, nullptr, hbuf);
    gemm_bf16<Fsz, Esz, 64, 1><<<dim3(512), 256, 0, stream>>>(hbuf, W2T, b2, x, out);
}

// Round 10
// 195.947 us; speedup vs baseline: 1.3660x; 1.1105x over previous
//
#include <hip/hip_runtime.h>
#include <hip/hip_bf16.h>

// B=4, S=2048, E=512, H=8, D=64, F=2048
// Attention via exact Gaussian-kernel Taylor factorization (R=16 terms), V folded after k-sum.
// Moments: ONE block per (b,h), block-local (r6's fence protocol removed; r8 confirmed fix).
// MLP GEMMs: 512-thr / 8-wave blocks, 3-stage counted-vmcnt pipeline,
// XOR bank-swizzle via pre-swizzled global_load_lds source + swizzled ds_read (rule #21),
// mlp2 BK=64 (halves barrier count). XCD swizzle (T1) kept.

#define Bsz 4
#define Ssz 2048
#define Esz 512
#define Hsz 8
#define Dsz 64
#define Fsz 2048
#define NR 16      // Taylor terms

typedef __attribute__((ext_vector_type(8))) short bf16x8;
typedef __attribute__((ext_vector_type(4))) float f32x4;

// 1/sqrt(n), n=1..15 (RS[0] unused)
__device__ __constant__ float RS[16] = {
    0.f, 1.0f, 0.70710678f, 0.57735027f, 0.5f, 0.44721360f, 0.40824829f,
    0.37796447f, 0.35355339f, 0.33333333f, 0.31622777f, 0.30151134f,
    0.28867513f, 0.27735010f, 0.26726124f, 0.25819889f};

static __device__ __forceinline__ void gload_lds16(const void* g, void* l) {
    __builtin_amdgcn_global_load_lds(
        (const __attribute__((address_space(1))) unsigned int*)g,
        (__attribute__((address_space(3))) unsigned int*)l, 16, 0, 0);
}

static __device__ __forceinline__ unsigned short f2bf(float f) {
    unsigned int b = __float_as_uint(f);
    b += 0x7FFFu + ((b >> 16) & 1u);
    return (unsigned short)(b >> 16);
}
static __device__ __forceinline__ float bf2f(unsigned short u) {
    return __int_as_float(((int)u) << 16);
}

// ---------------- K1: prep = LayerNorm(+Q/K, Xn bf16) | transpose W1 | transpose W2 ----------------
__global__ __launch_bounds__(256) void prep_kernel(
    const float* __restrict__ x,
    const float* __restrict__ Wq, const float* __restrict__ bq,
    const float* __restrict__ Wk, const float* __restrict__ bk,
    const float* __restrict__ W1, const float* __restrict__ W2,
    float* __restrict__ Qo, float* __restrict__ Ko, __hip_bfloat16* __restrict__ Xn,
    __hip_bfloat16* __restrict__ W1T, __hip_bfloat16* __restrict__ W2T)
{
    int bid = blockIdx.x;
    if (bid < 2048) {
        int wid = threadIdx.x >> 6, lane = threadIdx.x & 63;
        int tok = bid * 4 + wid;
        int b = tok >> 11, s = tok & 2047;

        const float* xrow = x + (size_t)tok * Esz;
        float4 v0 = *(const float4*)&xrow[lane * 8];
        float4 v1 = *(const float4*)&xrow[lane * 8 + 4];

        float sum = v0.x + v0.y + v0.z + v0.w + v1.x + v1.y + v1.z + v1.w;
        #pragma unroll
        for (int off = 32; off > 0; off >>= 1) sum += __shfl_xor(sum, off);
        float mean = sum * (1.0f / 512.0f);

        float d[8] = {v0.x - mean, v0.y - mean, v0.z - mean, v0.w - mean,
                      v1.x - mean, v1.y - mean, v1.z - mean, v1.w - mean};
        float ss = 0.f;
        #pragma unroll
        for (int j = 0; j < 8; ++j) ss = fmaf(d[j], d[j], ss);
        #pragma unroll
        for (int off = 32; off > 0; off >>= 1) ss += __shfl_xor(ss, off);
        float inv = rsqrtf(ss * (1.0f / 512.0f) + 1e-5f);

        float xn[8];
        #pragma unroll
        for (int j = 0; j < 8; ++j) xn[j] = d[j] * inv;

        int h = lane >> 3, dsub = (lane & 7) * 8;
        union { bf16x8 v; unsigned short u[8]; } pk;
        #pragma unroll
        for (int j = 0; j < 8; ++j) pk.u[j] = f2bf(xn[j]);
        *(bf16x8*)((unsigned short*)Xn + (((size_t)(b * Hsz + h) * Ssz + s) * Dsz + dsub)) = pk.v;

        float4 wqa = *(const float4*)&Wq[h * 64 + dsub];
        float4 wqb = *(const float4*)&Wq[h * 64 + dsub + 4];
        float4 wka = *(const float4*)&Wk[h * 64 + dsub];
        float4 wkb = *(const float4*)&Wk[h * 64 + dsub + 4];
        float pq = xn[0]*wqa.x + xn[1]*wqa.y + xn[2]*wqa.z + xn[3]*wqa.w
                 + xn[4]*wqb.x + xn[5]*wqb.y + xn[6]*wqb.z + xn[7]*wqb.w;
        float pkv = xn[0]*wka.x + xn[1]*wka.y + xn[2]*wka.z + xn[3]*wka.w
                  + xn[4]*wkb.x + xn[5]*wkb.y + xn[6]*wkb.z + xn[7]*wkb.w;
        #pragma unroll
        for (int off = 1; off < 8; off <<= 1) {
            pq  += __shfl_xor(pq, off);
            pkv += __shfl_xor(pkv, off);
        }
        if ((lane & 7) == 0) {
            int bh = b * Hsz + h;
            Qo[bh * Ssz + s] = pq + bq[h];
            Ko[bh * Ssz + s] = pkv + bk[h];
        }
        return;
    }

    __shared__ float tile[32][33];
    const float* in;
    __hip_bfloat16* outp;
    int R, C, bx, by;
    if (bid < 3072) {
        int tb = bid - 2048;
        in = W1; outp = W1T; R = Esz; C = Fsz;
        bx = tb & 63; by = tb >> 6;
    } else {
        int tb = bid - 3072;
        in = W2; outp = W2T; R = Fsz; C = Esz;
        bx = tb & 15; by = tb >> 4;
    }
    int t = threadIdx.x;
    int tc = t & 31, tr = t >> 5;
    #pragma unroll
    for (int i = 0; i < 4; ++i) {
        int rr = by * 32 + tr + i * 8, cc = bx * 32 + tc;
        tile[tr + i * 8][tc] = in[(size_t)rr * C + cc];
    }
    __syncthreads();
    #pragma unroll
    for (int i = 0; i < 4; ++i) {
        int ro = bx * 32 + tr + i * 8, co = by * 32 + tc;
        outp[(size_t)ro * R + co] = __float2bfloat16(tile[tc][tr + i * 8]);
    }
}

// ---------------- K2: moments, ONE block per bh (block-local, no fences) ----------------
__global__ __launch_bounds__(512) void attn_moments_block(
    const float* __restrict__ Kv, const __hip_bfloat16* __restrict__ Xn,
    const float* __restrict__ Wv, const float* __restrict__ bvp,
    float* __restrict__ M)
{
    int bh = blockIdx.x, h = bh & 7;
    int t = threadIdx.x;
    __shared__ float Wt[512][17];
    __shared__ float Gf[NR * 68];

    int w = t >> 6, lane = t & 63;
    int kk = lane >> 3, dg = lane & 7;
    int ng = w * 2;
    float acc[2][8] = {};
    float dacc[2] = {};

    const unsigned short* xb = (const unsigned short*)Xn + (size_t)bh * Ssz * Dsz + dg * 8;

    for (int c = 0; c < Ssz / 512; ++c) {
        int k0 = c * 512;
        float kv = Kv[bh * Ssz + k0 + t];
        float wn = __expf(-0.125f * kv * kv);
        float half = 0.5f * kv;
        __syncthreads();
        Wt[t][0] = wn;
        #pragma unroll
        for (int n = 1; n < NR; ++n) { wn *= half * RS[n]; Wt[t][n] = wn; }
        __syncthreads();

        for (int kc = 0; kc < 512 / 8; ++kc) {
            int kl = kc * 8 + kk;
            bf16x8 xv = *(const bf16x8*)&xb[(size_t)(k0 + kl) * Dsz];
            float xf[8];
            #pragma unroll
            for (int e = 0; e < 8; ++e) xf[e] = bf2f((unsigned short)xv[e]);
            #pragma unroll
            for (int n = 0; n < 2; ++n) {
                float wt = Wt[kl][ng + n];
                dacc[n] += wt;
                #pragma unroll
                for (int e = 0; e < 8; ++e) acc[n][e] = fmaf(wt, xf[e], acc[n][e]);
            }
        }
    }

    #pragma unroll
    for (int off = 8; off < 64; off <<= 1) {
        #pragma unroll
        for (int n = 0; n < 2; ++n) {
            dacc[n] += __shfl_xor(dacc[n], off);
            #pragma unroll
            for (int e = 0; e < 8; ++e) acc[n][e] += __shfl_xor(acc[n][e], off);
        }
    }
    if (lane < 8) {
        #pragma unroll
        for (int n = 0; n < 2; ++n) {
            float* gp = &Gf[(ng + n) * 68 + dg * 8];
            float4 lo = {acc[n][0], acc[n][1], acc[n][2], acc[n][3]};
            float4 hi = {acc[n][4], acc[n][5], acc[n][6], acc[n][7]};
            *(float4*)gp = lo;
            *(float4*)(gp + 4) = hi;
        }
    }
    if (lane == 0) {
        #pragma unroll
        for (int n = 0; n < 2; ++n) Gf[(ng + n) * 68 + 64] = dacc[n];
    }
    __syncthreads();

    #pragma unroll
    for (int rep = 0; rep < 2; ++rep) {
        int o = t + rep * 512;
        int n = o >> 6, dd = o & 63;
        float den = Gf[n * 68 + 64];
        float accv = den * bvp[h * 64 + dd];
        const float* wv = Wv + ((size_t)h * 64) * 64 + dd;
        #pragma unroll
        for (int e = 0; e < 64; ++e) accv = fmaf(Gf[n * 68 + e], wv[(size_t)e * 64], accv);
        M[(size_t)bh * NR * 68 + n * 68 + dd] = accv;
        if (dd == 0) M[(size_t)bh * NR * 68 + n * 68 + 64] = den;
    }
}

// ---------------- K3: apply Q-side, write head_out as bf16 [8192,512] ----------------
__global__ __launch_bounds__(256) void attn_apply(
    const float* __restrict__ Qv, const float* __restrict__ M, __hip_bfloat16* __restrict__ A1)
{
    int tok = blockIdx.x;
    int b = tok >> 11, s = tok & 2047;
    int t = threadIdx.x;
    #pragma unroll
    for (int rep = 0; rep < 2; ++rep) {
        int e = t + rep * 256;
        int h = e >> 6, dd = e & 63;
        int bh = b * 8 + h;
        float q = Qv[bh * Ssz + s];
        const float* Mb = M + (size_t)bh * NR * 68;
        float half = 0.5f * q;
        float phi = 1.0f;
        float num = Mb[dd], den = Mb[64];
        #pragma unroll
        for (int n = 1; n < NR; ++n) {
            phi *= half * RS[n];
            num = fmaf(phi, Mb[n * 68 + dd], num);
            den = fmaf(phi, Mb[n * 68 + 64], den);
        }
        A1[(size_t)tok * Esz + e] = __float2bfloat16(num / den);
    }
}

// ---------------- K4/K5: bf16 MFMA GEMM, 8 waves, 3-stage counted-vmcnt, bank-swizzled LDS ----
// C = A[M=8192,K] * Bt[N,K]^T.  Tile 128 x BN, K-step BK, 512 threads (8 waves, WRW x WCW grid).
// LDS layout: linear [row][BK]; element (r, slot c) stored at slot c ^ SWZ(r) where
// SWZ = (r>>1)&3 for BK=32 (64B rows) / r&7 for BK=64 (128B rows) -> 2-way conflicts (free).
// global_load_lds keeps a LINEAR dest (lane*16) and pre-swizzles the SOURCE column (rule #21).
// EPI=0: out bf16 = gelu(acc+bias). EPI=1: out f32 = acc+bias+resid.
template <int KDIM, int NDIM, int BN, int BK, int WRW, int EPI>
__global__ __launch_bounds__(512, 4) void gemm_bf16(
    const __hip_bfloat16* __restrict__ A, const __hip_bfloat16* __restrict__ Bt,
    const float* __restrict__ bias, const float* __restrict__ resid,
    void* __restrict__ Out)
{
    constexpr int NT = KDIM / BK;            // K-steps
    constexpr int WCW = 8 / WRW;             // waves along N
    constexpr int MROWS = 128 / WRW;         // rows per wave
    constexpr int MF = MROWS / 16;           // M-frags per wave
    constexpr int NCOLS = BN / WCW;          // cols per wave
    constexpr int NF = NCOLS / 16;           // N-frags per wave
    constexpr int KS = BK / 32;              // k-slices per step
    constexpr int NSLOT = BK / 8;            // 16B slots per row
    constexpr int ACALLS = BK / 32;          // A gload calls per stage (512 thr x 8 elem)
    constexpr int LPS = ACALLS + (BN * BK) / 4096;  // loads/stage per thread (uniform)
    constexpr int NWGX = NDIM / BN;
    constexpr int NWG = NWGX * 64;           // 8192/128 = 64 M-tiles

    __shared__ unsigned short As[3][128][BK];
    __shared__ unsigned short Bs[3][BN][BK];

    int t = threadIdx.x;
    int w = t >> 6, lane = t & 63;
    int wr = w / WCW, wc = w % WCW;

    // XCD-aware bijective swizzle (NWG % 8 == 0 for both instantiations)
    int orig = blockIdx.x;
    int swzb = (orig & 7) * (NWG / 8) + (orig >> 3);
    int bm = (swzb / NWGX) * 128;
    int bn = (swzb % NWGX) * BN;

    f32x4 acc[MF][NF] = {};

    auto rswz = [](int r) -> int { return (BK == 32) ? ((r >> 1) & 3) : (r & 7); };

    const int tr = t / NSLOT;                // staging row within a call
    const int cgs = t & (NSLOT - 1);         // staging slot (linear dest)

    auto stage = [&](int kt, int buf) {
        int k0 = kt * BK;
        #pragma unroll
        for (int a = 0; a < ACALLS; ++a) {
            int r = a * (4096 / BK) + tr;
            int srcc = cgs ^ rswz(r);
            gload_lds16(&A[(size_t)(bm + r) * KDIM + k0 + srcc * 8], &As[buf][r][cgs * 8]);
        }
        {
            int r = tr;                       // B rows per call = 4096/BK == BN for both configs
            int srcc = cgs ^ rswz(r);
            gload_lds16(&Bt[(size_t)(bn + r) * KDIM + k0 + srcc * 8], &Bs[buf][r][cgs * 8]);
        }
    };
    auto wait_stage = [&](bool more_inflight) {
        if (more_inflight) {
            if constexpr (LPS == 2) asm volatile("s_waitcnt vmcnt(2)" ::: "memory");
            else                    asm volatile("s_waitcnt vmcnt(3)" ::: "memory");
        } else {
            asm volatile("s_waitcnt vmcnt(0)" ::: "memory");
        }
    };

    stage(0, 0);
    stage(1, 1);
    wait_stage(true);
    __builtin_amdgcn_s_barrier();
    __builtin_amdgcn_sched_barrier(0);

    const int l15 = lane & 15, lg = lane >> 4;

    for (int kt = 0; kt < NT; ++kt) {
        int cb = kt % 3;
        if (kt + 2 < NT) stage(kt + 2, (kt + 2) % 3);

        bf16x8 af[MF][KS], bfv[NF][KS];
        #pragma unroll
        for (int i = 0; i < MF; ++i) {
            int rr = wr * MROWS + i * 16 + l15;
            #pragma unroll
            for (int ks = 0; ks < KS; ++ks) {
                int slot = (lg + ks * 4) ^ rswz(rr);
                af[i][ks] = *(const bf16x8*)&As[cb][rr][slot * 8];
            }
        }
        #pragma unroll
        for (int j = 0; j < NF; ++j) {
            int rr = wc * NCOLS + j * 16 + l15;
            #pragma unroll
            for (int ks = 0; ks < KS; ++ks) {
                int slot = (lg + ks * 4) ^ rswz(rr);
                bfv[j][ks] = *(const bf16x8*)&Bs[cb][rr][slot * 8];
            }
        }
        #pragma unroll
        for (int i = 0; i < MF; ++i)
            #pragma unroll
            for (int j = 0; j < NF; ++j)
                #pragma unroll
                for (int ks = 0; ks < KS; ++ks)
                    acc[i][j] = __builtin_amdgcn_mfma_f32_16x16x32_bf16(af[i][ks], bfv[j][ks], acc[i][j], 0, 0, 0);

        if (kt + 1 < NT) {
            wait_stage(kt + 2 < NT);
            __builtin_amdgcn_s_barrier();
            __builtin_amdgcn_sched_barrier(0);
        }
    }

    int col0 = lane & 15, rowg = lane >> 4;
    #pragma unroll
    for (int i = 0; i < MF; ++i) {
        #pragma unroll
        for (int j = 0; j < NF; ++j) {
            #pragma unroll
            for (int v = 0; v < 4; ++v) {
                int m = bm + wr * MROWS + i * 16 + rowg * 4 + v;
                int n = bn + wc * NCOLS + j * 16 + col0;
                float val = acc[i][j][v] + bias[n];
                if (EPI == 0) {
                    float g = 0.5f * val * (1.0f + erff(val * 0.70710678f));
                    ((__hip_bfloat16*)Out)[(size_t)m * NDIM + n] = __float2bfloat16(g);
                } else {
                    size_t idx = (size_t)m * NDIM + n;
                    ((float*)Out)[idx] = val + resid[idx];
                }
            }
        }
    }
}

extern "C" void kernel_launch(void* const* d_in, const int* in_sizes, int n_in,
                              void* d_out, int out_size, void* d_ws, size_t ws_size,
                              hipStream_t stream) {
    const float* x  = (const float*)d_in[0];
    const float* Wv = (const float*)d_in[1];
    const float* bv = (const float*)d_in[2];
    const float* Wq = (const float*)d_in[3];
    const float* bq = (const float*)d_in[4];
    const float* Wk = (const float*)d_in[5];
    const float* bk = (const float*)d_in[6];
    const float* W1 = (const float*)d_in[7];
    const float* b1 = (const float*)d_in[8];
    const float* W2 = (const float*)d_in[9];
    const float* b2 = (const float*)d_in[10];
    float* out = (float*)d_out;

    char* ws = (char*)d_ws;
    float* Qb    = (float*)(ws + 0);                         // 256 KB
    float* Kb    = (float*)(ws + 262144);                    // 256 KB
    __hip_bfloat16* Xn = (__hip_bfloat16*)(ws + 524288);     // 8 MB  [bh][s][d]
    __hip_bfloat16* A1 = (__hip_bfloat16*)(ws + 8912896);    // 8 MB
    float* Mfull = (float*)(ws + 17301504);                  // 139 KB
    __hip_bfloat16* W1T  = (__hip_bfloat16*)(ws + 17441024); // 2 MB
    __hip_bfloat16* W2T  = (__hip_bfloat16*)(ws + 19538176); // 2 MB
    __hip_bfloat16* hbuf = (__hip_bfloat16*)(ws + 21635328); // 32 MB

    prep_kernel<<<dim3(4096), 256, 0, stream>>>(x, Wq, bq, Wk, bk, W1, W2, Qb, Kb, Xn, W1T, W2T);
    attn_moments_block<<<dim3(Bsz * Hsz), 512, 0, stream>>>(Kb, Xn, Wv, bv, Mfull);
    attn_apply<<<dim3(Bsz * Ssz), 256, 0, stream>>>(Qb, Mfull, A1);
    // mlp1: K=512, N=2048, tile 128x128, BK=32, waves 2x4
    gemm_bf16<Esz, Fsz, 128, 32, 2, 0><<<dim3(1024), 512, 0, stream>>>(A1, W1T, b1, nullptr, hbuf);
    // mlp2: K=2048, N=512, tile 128x64, BK=64, waves 4x2
    gemm_bf16<Fsz, Esz, 64, 64, 4, 1><<<dim3(512), 512, 0, stream>>>(hbuf, W2T, b2, x, out);
}

// Round 11
// 194.903 us; speedup vs baseline: 1.3733x; 1.0054x over previous
//
#include <hip/hip_runtime.h>
#include <hip/hip_bf16.h>

// B=4, S=2048, E=512, H=8, D=64, F=2048
// Attention via exact Gaussian-kernel Taylor factorization (R=16 terms), V folded after k-sum.
// Moments: ONE block per (b,h), block-local. MLP GEMMs: 512-thr / 8-wave blocks, 3-stage
// counted-vmcnt pipeline, XOR bank-swizzle (rule #21), XCD swizzle (T1), s_setprio (T5).
// r11: mlp1 tile 128x256 (16 MFMA/wave/step, 2x work per barrier), setprio both gemms.

#define Bsz 4
#define Ssz 2048
#define Esz 512
#define Hsz 8
#define Dsz 64
#define Fsz 2048
#define NR 16      // Taylor terms

typedef __attribute__((ext_vector_type(8))) short bf16x8;
typedef __attribute__((ext_vector_type(4))) float f32x4;

// 1/sqrt(n), n=1..15 (RS[0] unused)
__device__ __constant__ float RS[16] = {
    0.f, 1.0f, 0.70710678f, 0.57735027f, 0.5f, 0.44721360f, 0.40824829f,
    0.37796447f, 0.35355339f, 0.33333333f, 0.31622777f, 0.30151134f,
    0.28867513f, 0.27735010f, 0.26726124f, 0.25819889f};

static __device__ __forceinline__ void gload_lds16(const void* g, void* l) {
    __builtin_amdgcn_global_load_lds(
        (const __attribute__((address_space(1))) unsigned int*)g,
        (__attribute__((address_space(3))) unsigned int*)l, 16, 0, 0);
}

static __device__ __forceinline__ unsigned short f2bf(float f) {
    unsigned int b = __float_as_uint(f);
    b += 0x7FFFu + ((b >> 16) & 1u);
    return (unsigned short)(b >> 16);
}
static __device__ __forceinline__ float bf2f(unsigned short u) {
    return __int_as_float(((int)u) << 16);
}

// ---------------- K1: prep = LayerNorm(+Q/K, Xn bf16) | transpose W1 | transpose W2 ----------------
__global__ __launch_bounds__(256) void prep_kernel(
    const float* __restrict__ x,
    const float* __restrict__ Wq, const float* __restrict__ bq,
    const float* __restrict__ Wk, const float* __restrict__ bk,
    const float* __restrict__ W1, const float* __restrict__ W2,
    float* __restrict__ Qo, float* __restrict__ Ko, __hip_bfloat16* __restrict__ Xn,
    __hip_bfloat16* __restrict__ W1T, __hip_bfloat16* __restrict__ W2T)
{
    int bid = blockIdx.x;
    if (bid < 2048) {
        int wid = threadIdx.x >> 6, lane = threadIdx.x & 63;
        int tok = bid * 4 + wid;
        int b = tok >> 11, s = tok & 2047;

        const float* xrow = x + (size_t)tok * Esz;
        float4 v0 = *(const float4*)&xrow[lane * 8];
        float4 v1 = *(const float4*)&xrow[lane * 8 + 4];

        float sum = v0.x + v0.y + v0.z + v0.w + v1.x + v1.y + v1.z + v1.w;
        #pragma unroll
        for (int off = 32; off > 0; off >>= 1) sum += __shfl_xor(sum, off);
        float mean = sum * (1.0f / 512.0f);

        float d[8] = {v0.x - mean, v0.y - mean, v0.z - mean, v0.w - mean,
                      v1.x - mean, v1.y - mean, v1.z - mean, v1.w - mean};
        float ss = 0.f;
        #pragma unroll
        for (int j = 0; j < 8; ++j) ss = fmaf(d[j], d[j], ss);
        #pragma unroll
        for (int off = 32; off > 0; off >>= 1) ss += __shfl_xor(ss, off);
        float inv = rsqrtf(ss * (1.0f / 512.0f) + 1e-5f);

        float xn[8];
        #pragma unroll
        for (int j = 0; j < 8; ++j) xn[j] = d[j] * inv;

        int h = lane >> 3, dsub = (lane & 7) * 8;
        union { bf16x8 v; unsigned short u[8]; } pk;
        #pragma unroll
        for (int j = 0; j < 8; ++j) pk.u[j] = f2bf(xn[j]);
        *(bf16x8*)((unsigned short*)Xn + (((size_t)(b * Hsz + h) * Ssz + s) * Dsz + dsub)) = pk.v;

        float4 wqa = *(const float4*)&Wq[h * 64 + dsub];
        float4 wqb = *(const float4*)&Wq[h * 64 + dsub + 4];
        float4 wka = *(const float4*)&Wk[h * 64 + dsub];
        float4 wkb = *(const float4*)&Wk[h * 64 + dsub + 4];
        float pq = xn[0]*wqa.x + xn[1]*wqa.y + xn[2]*wqa.z + xn[3]*wqa.w
                 + xn[4]*wqb.x + xn[5]*wqb.y + xn[6]*wqb.z + xn[7]*wqb.w;
        float pkv = xn[0]*wka.x + xn[1]*wka.y + xn[2]*wka.z + xn[3]*wka.w
                  + xn[4]*wkb.x + xn[5]*wkb.y + xn[6]*wkb.z + xn[7]*wkb.w;
        #pragma unroll
        for (int off = 1; off < 8; off <<= 1) {
            pq  += __shfl_xor(pq, off);
            pkv += __shfl_xor(pkv, off);
        }
        if ((lane & 7) == 0) {
            int bh = b * Hsz + h;
            Qo[bh * Ssz + s] = pq + bq[h];
            Ko[bh * Ssz + s] = pkv + bk[h];
        }
        return;
    }

    __shared__ float tile[32][33];
    const float* in;
    __hip_bfloat16* outp;
    int R, C, bx, by;
    if (bid < 3072) {
        int tb = bid - 2048;
        in = W1; outp = W1T; R = Esz; C = Fsz;
        bx = tb & 63; by = tb >> 6;
    } else {
        int tb = bid - 3072;
        in = W2; outp = W2T; R = Fsz; C = Esz;
        bx = tb & 15; by = tb >> 4;
    }
    int t = threadIdx.x;
    int tc = t & 31, tr = t >> 5;
    #pragma unroll
    for (int i = 0; i < 4; ++i) {
        int rr = by * 32 + tr + i * 8, cc = bx * 32 + tc;
        tile[tr + i * 8][tc] = in[(size_t)rr * C + cc];
    }
    __syncthreads();
    #pragma unroll
    for (int i = 0; i < 4; ++i) {
        int ro = bx * 32 + tr + i * 8, co = by * 32 + tc;
        outp[(size_t)ro * R + co] = __float2bfloat16(tile[tc][tr + i * 8]);
    }
}

// ---------------- K2: moments, ONE block per bh (block-local, no fences) ----------------
__global__ __launch_bounds__(512) void attn_moments_block(
    const float* __restrict__ Kv, const __hip_bfloat16* __restrict__ Xn,
    const float* __restrict__ Wv, const float* __restrict__ bvp,
    float* __restrict__ M)
{
    int bh = blockIdx.x, h = bh & 7;
    int t = threadIdx.x;
    __shared__ float Wt[512][17];
    __shared__ float Gf[NR * 68];

    int w = t >> 6, lane = t & 63;
    int kk = lane >> 3, dg = lane & 7;
    int ng = w * 2;
    float acc[2][8] = {};
    float dacc[2] = {};

    const unsigned short* xb = (const unsigned short*)Xn + (size_t)bh * Ssz * Dsz + dg * 8;

    for (int c = 0; c < Ssz / 512; ++c) {
        int k0 = c * 512;
        float kv = Kv[bh * Ssz + k0 + t];
        float wn = __expf(-0.125f * kv * kv);
        float half = 0.5f * kv;
        __syncthreads();
        Wt[t][0] = wn;
        #pragma unroll
        for (int n = 1; n < NR; ++n) { wn *= half * RS[n]; Wt[t][n] = wn; }
        __syncthreads();

        for (int kc = 0; kc < 512 / 8; ++kc) {
            int kl = kc * 8 + kk;
            bf16x8 xv = *(const bf16x8*)&xb[(size_t)(k0 + kl) * Dsz];
            float xf[8];
            #pragma unroll
            for (int e = 0; e < 8; ++e) xf[e] = bf2f((unsigned short)xv[e]);
            #pragma unroll
            for (int n = 0; n < 2; ++n) {
                float wt = Wt[kl][ng + n];
                dacc[n] += wt;
                #pragma unroll
                for (int e = 0; e < 8; ++e) acc[n][e] = fmaf(wt, xf[e], acc[n][e]);
            }
        }
    }

    #pragma unroll
    for (int off = 8; off < 64; off <<= 1) {
        #pragma unroll
        for (int n = 0; n < 2; ++n) {
            dacc[n] += __shfl_xor(dacc[n], off);
            #pragma unroll
            for (int e = 0; e < 8; ++e) acc[n][e] += __shfl_xor(acc[n][e], off);
        }
    }
    if (lane < 8) {
        #pragma unroll
        for (int n = 0; n < 2; ++n) {
            float* gp = &Gf[(ng + n) * 68 + dg * 8];
            float4 lo = {acc[n][0], acc[n][1], acc[n][2], acc[n][3]};
            float4 hi = {acc[n][4], acc[n][5], acc[n][6], acc[n][7]};
            *(float4*)gp = lo;
            *(float4*)(gp + 4) = hi;
        }
    }
    if (lane == 0) {
        #pragma unroll
        for (int n = 0; n < 2; ++n) Gf[(ng + n) * 68 + 64] = dacc[n];
    }
    __syncthreads();

    #pragma unroll
    for (int rep = 0; rep < 2; ++rep) {
        int o = t + rep * 512;
        int n = o >> 6, dd = o & 63;
        float den = Gf[n * 68 + 64];
        float accv = den * bvp[h * 64 + dd];
        const float* wv = Wv + ((size_t)h * 64) * 64 + dd;
        #pragma unroll
        for (int e = 0; e < 64; ++e) accv = fmaf(Gf[n * 68 + e], wv[(size_t)e * 64], accv);
        M[(size_t)bh * NR * 68 + n * 68 + dd] = accv;
        if (dd == 0) M[(size_t)bh * NR * 68 + n * 68 + 64] = den;
    }
}

// ---------------- K3: apply Q-side, write head_out as bf16 [8192,512] ----------------
__global__ __launch_bounds__(256) void attn_apply(
    const float* __restrict__ Qv, const float* __restrict__ M, __hip_bfloat16* __restrict__ A1)
{
    int tok = blockIdx.x;
    int b = tok >> 11, s = tok & 2047;
    int t = threadIdx.x;
    #pragma unroll
    for (int rep = 0; rep < 2; ++rep) {
        int e = t + rep * 256;
        int h = e >> 6, dd = e & 63;
        int bh = b * 8 + h;
        float q = Qv[bh * Ssz + s];
        const float* Mb = M + (size_t)bh * NR * 68;
        float half = 0.5f * q;
        float phi = 1.0f;
        float num = Mb[dd], den = Mb[64];
        #pragma unroll
        for (int n = 1; n < NR; ++n) {
            phi *= half * RS[n];
            num = fmaf(phi, Mb[n * 68 + dd], num);
            den = fmaf(phi, Mb[n * 68 + 64], den);
        }
        A1[(size_t)tok * Esz + e] = __float2bfloat16(num / den);
    }
}

// ---------------- K4/K5: bf16 MFMA GEMM, 8 waves, 3-stage counted-vmcnt, bank-swizzled LDS ----
// C = A[M=8192,K] * Bt[N,K]^T.  Tile 128 x BN, K-step BK, 512 threads (8 waves, WRW x WCW).
// LDS: linear [row][BK]; slot c holds global col c ^ SWZ(r); gload src pre-swizzled (rule #21).
// setprio(1) around the MFMA cluster (T5 - counted-vmcnt gives wave role diversity).
// EPI=0: out bf16 = gelu(acc+bias). EPI=1: out f32 = acc+bias+resid.
template <int KDIM, int NDIM, int BN, int BK, int WRW, int EPI>
__global__ __launch_bounds__(512, 4) void gemm_bf16(
    const __hip_bfloat16* __restrict__ A, const __hip_bfloat16* __restrict__ Bt,
    const float* __restrict__ bias, const float* __restrict__ resid,
    void* __restrict__ Out)
{
    constexpr int NT = KDIM / BK;            // K-steps
    constexpr int WCW = 8 / WRW;             // waves along N
    constexpr int MROWS = 128 / WRW;         // rows per wave
    constexpr int MF = MROWS / 16;           // M-frags per wave
    constexpr int NCOLS = BN / WCW;          // cols per wave
    constexpr int NF = NCOLS / 16;           // N-frags per wave
    constexpr int KS = BK / 32;              // k-slices per step
    constexpr int NSLOT = BK / 8;            // 16B slots per row
    constexpr int RPC = 4096 / BK;           // rows covered per gload call (512 thr x 8 elem)
    constexpr int ACALLS = 128 / RPC;        // A gload calls per stage
    constexpr int BCALLS = BN / RPC;         // B gload calls per stage
    constexpr int LPS = ACALLS + BCALLS;     // loads/stage per thread (uniform)
    constexpr int NWGX = NDIM / BN;
    constexpr int NWG = NWGX * 64;           // 8192/128 = 64 M-tiles

    __shared__ unsigned short As[3][128][BK];
    __shared__ unsigned short Bs[3][BN][BK];

    int t = threadIdx.x;
    int w = t >> 6, lane = t & 63;
    int wr = w / WCW, wc = w % WCW;

    // XCD-aware bijective swizzle (NWG % 8 == 0 for both instantiations)
    int orig = blockIdx.x;
    int swzb = (orig & 7) * (NWG / 8) + (orig >> 3);
    int bm = (swzb / NWGX) * 128;
    int bn = (swzb % NWGX) * BN;

    f32x4 acc[MF][NF] = {};

    auto rswz = [](int r) -> int { return (BK == 32) ? ((r >> 1) & 3) : (r & 7); };

    const int tr = t / NSLOT;                // staging row within a call
    const int cgs = t & (NSLOT - 1);         // staging slot (linear dest)

    auto stage = [&](int kt, int buf) {
        int k0 = kt * BK;
        #pragma unroll
        for (int a = 0; a < ACALLS; ++a) {
            int r = a * RPC + tr;
            int srcc = cgs ^ rswz(r);
            gload_lds16(&A[(size_t)(bm + r) * KDIM + k0 + srcc * 8], &As[buf][r][cgs * 8]);
        }
        #pragma unroll
        for (int b = 0; b < BCALLS; ++b) {
            int r = b * RPC + tr;
            int srcc = cgs ^ rswz(r);
            gload_lds16(&Bt[(size_t)(bn + r) * KDIM + k0 + srcc * 8], &Bs[buf][r][cgs * 8]);
        }
    };
    auto wait_stage = [&](bool more_inflight) {
        if (more_inflight) {
            if constexpr (LPS == 2)      asm volatile("s_waitcnt vmcnt(2)" ::: "memory");
            else if constexpr (LPS == 3) asm volatile("s_waitcnt vmcnt(3)" ::: "memory");
            else                         asm volatile("s_waitcnt vmcnt(4)" ::: "memory");
        } else {
            asm volatile("s_waitcnt vmcnt(0)" ::: "memory");
        }
    };

    stage(0, 0);
    stage(1, 1);
    wait_stage(true);
    __builtin_amdgcn_s_barrier();
    __builtin_amdgcn_sched_barrier(0);

    const int l15 = lane & 15, lg = lane >> 4;

    for (int kt = 0; kt < NT; ++kt) {
        int cb = kt % 3;
        if (kt + 2 < NT) stage(kt + 2, (kt + 2) % 3);

        bf16x8 af[MF][KS], bfv[NF][KS];
        #pragma unroll
        for (int i = 0; i < MF; ++i) {
            int rr = wr * MROWS + i * 16 + l15;
            #pragma unroll
            for (int ks = 0; ks < KS; ++ks) {
                int slot = (lg + ks * 4) ^ rswz(rr);
                af[i][ks] = *(const bf16x8*)&As[cb][rr][slot * 8];
            }
        }
        #pragma unroll
        for (int j = 0; j < NF; ++j) {
            int rr = wc * NCOLS + j * 16 + l15;
            #pragma unroll
            for (int ks = 0; ks < KS; ++ks) {
                int slot = (lg + ks * 4) ^ rswz(rr);
                bfv[j][ks] = *(const bf16x8*)&Bs[cb][rr][slot * 8];
            }
        }
        __builtin_amdgcn_s_setprio(1);
        #pragma unroll
        for (int i = 0; i < MF; ++i)
            #pragma unroll
            for (int j = 0; j < NF; ++j)
                #pragma unroll
                for (int ks = 0; ks < KS; ++ks)
                    acc[i][j] = __builtin_amdgcn_mfma_f32_16x16x32_bf16(af[i][ks], bfv[j][ks], acc[i][j], 0, 0, 0);
        __builtin_amdgcn_s_setprio(0);

        if (kt + 1 < NT) {
            wait_stage(kt + 2 < NT);
            __builtin_amdgcn_s_barrier();
            __builtin_amdgcn_sched_barrier(0);
        }
    }

    int col0 = lane & 15, rowg = lane >> 4;
    #pragma unroll
    for (int i = 0; i < MF; ++i) {
        #pragma unroll
        for (int j = 0; j < NF; ++j) {
            #pragma unroll
            for (int v = 0; v < 4; ++v) {
                int m = bm + wr * MROWS + i * 16 + rowg * 4 + v;
                int n = bn + wc * NCOLS + j * 16 + col0;
                float val = acc[i][j][v] + bias[n];
                if (EPI == 0) {
                    float g = 0.5f * val * (1.0f + erff(val * 0.70710678f));
                    ((__hip_bfloat16*)Out)[(size_t)m * NDIM + n] = __float2bfloat16(g);
                } else {
                    size_t idx = (size_t)m * NDIM + n;
                    ((float*)Out)[idx] = val + resid[idx];
                }
            }
        }
    }
}

extern "C" void kernel_launch(void* const* d_in, const int* in_sizes, int n_in,
                              void* d_out, int out_size, void* d_ws, size_t ws_size,
                              hipStream_t stream) {
    const float* x  = (const float*)d_in[0];
    const float* Wv = (const float*)d_in[1];
    const float* bv = (const float*)d_in[2];
    const float* Wq = (const float*)d_in[3];
    const float* bq = (const float*)d_in[4];
    const float* Wk = (const float*)d_in[5];
    const float* bk = (const float*)d_in[6];
    const float* W1 = (const float*)d_in[7];
    const float* b1 = (const float*)d_in[8];
    const float* W2 = (const float*)d_in[9];
    const float* b2 = (const float*)d_in[10];
    float* out = (float*)d_out;

    char* ws = (char*)d_ws;
    float* Qb    = (float*)(ws + 0);                         // 256 KB
    float* Kb    = (float*)(ws + 262144);                    // 256 KB
    __hip_bfloat16* Xn = (__hip_bfloat16*)(ws + 524288);     // 8 MB  [bh][s][d]
    __hip_bfloat16* A1 = (__hip_bfloat16*)(ws + 8912896);    // 8 MB
    float* Mfull = (float*)(ws + 17301504);                  // 139 KB
    __hip_bfloat16* W1T  = (__hip_bfloat16*)(ws + 17441024); // 2 MB
    __hip_bfloat16* W2T  = (__hip_bfloat16*)(ws + 19538176); // 2 MB
    __hip_bfloat16* hbuf = (__hip_bfloat16*)(ws + 21635328); // 32 MB

    prep_kernel<<<dim3(4096), 256, 0, stream>>>(x, Wq, bq, Wk, bk, W1, W2, Qb, Kb, Xn, W1T, W2T);
    attn_moments_block<<<dim3(Bsz * Hsz), 512, 0, stream>>>(Kb, Xn, Wv, bv, Mfull);
    attn_apply<<<dim3(Bsz * Ssz), 256, 0, stream>>>(Qb, Mfull, A1);
    // mlp1: K=512, N=2048, tile 128x256, BK=32, waves 2x4 (16 MFMA/wave/step)
    gemm_bf16<Esz, Fsz, 256, 32, 2, 0><<<dim3(512), 512, 0, stream>>>(A1, W1T, b1, nullptr, hbuf);
    // mlp2: K=2048, N=512, tile 128x64, BK=64, waves 4x2
    gemm_bf16<Fsz, Esz, 64, 64, 4, 1><<<dim3(512), 512, 0, stream>>>(hbuf, W2T, b2, x, out);
}